// Round 1
// baseline (326.878 us; speedup 1.0000x reference)
//
#include <hip/hip_runtime.h>
#include <hip/hip_bf16.h>
#include <stdint.h>

#define DMODEL 768
#define NHEADS 12
#define DK 64
#define BATCH 2
#define SEQ 2048

typedef __attribute__((ext_vector_type(8))) short shortx8;
typedef __attribute__((ext_vector_type(4))) float f32x4;
typedef __attribute__((ext_vector_type(8))) __bf16 bf16v8;

static __device__ __forceinline__ float bf2f(ushort u) {
  union { uint32_t i; float f; } v; v.i = ((uint32_t)u) << 16; return v.f;
}
static __device__ __forceinline__ ushort f2bf(float f) {
  union { float f; uint32_t i; } v; v.f = f;
  uint32_t r = v.i + 0x7fffu + ((v.i >> 16) & 1u);
  return (ushort)(r >> 16);
}

// SFINAE hedge: the gfx950 bf16 MFMA builtin takes v8i16 on some toolchains,
// v8bf16 on others. Overload 1 is picked when short8 works; overload 2 bitcasts.
template <typename AB>
static __device__ __forceinline__ auto mfma_impl(AB a, AB b, f32x4 c, int)
    -> decltype(__builtin_amdgcn_mfma_f32_16x16x32_bf16(a, b, c, 0, 0, 0)) {
  return __builtin_amdgcn_mfma_f32_16x16x32_bf16(a, b, c, 0, 0, 0);
}
template <typename AB>
static __device__ __forceinline__ f32x4 mfma_impl(AB a, AB b, f32x4 c, long) {
  bf16v8 av, bv;
  __builtin_memcpy(&av, &a, 16);
  __builtin_memcpy(&bv, &b, 16);
  return __builtin_amdgcn_mfma_f32_16x16x32_bf16(av, bv, c, 0, 0, 0);
}
static __device__ __forceinline__ f32x4 MFMA(shortx8 a, shortx8 b, f32x4 c) {
  return mfma_impl(a, b, c, 0);
}

// ---------------------------------------------------------------------------
// Prep: W[k][n] f32 -> WT_hi/WT_lo[n][k] bf16 (split), 4 matrices concatenated.
// 32x32 LDS-tiled transpose, coalesced both directions.
// ---------------------------------------------------------------------------
__global__ __launch_bounds__(256) void wsplit_kernel(
    const float* __restrict__ W0, const float* __restrict__ W1,
    const float* __restrict__ W2, const float* __restrict__ W3,
    ushort* __restrict__ hiT, ushort* __restrict__ loT) {
  __shared__ float tile[32][33];
  const int wsel = blockIdx.z;
  const float* W = wsel == 0 ? W0 : wsel == 1 ? W1 : wsel == 2 ? W2 : W3;
  const int k0 = blockIdx.x * 32, n0 = blockIdx.y * 32;
  const int tx = threadIdx.x & 31, ty = threadIdx.x >> 5;  // ty: 0..7
#pragma unroll
  for (int i = 0; i < 4; i++) {
    int kl = ty + i * 8;
    tile[kl][tx] = W[(size_t)(k0 + kl) * DMODEL + n0 + tx];
  }
  __syncthreads();
  ushort* hi = hiT + (size_t)wsel * DMODEL * DMODEL;
  ushort* lo = loT + (size_t)wsel * DMODEL * DMODEL;
#pragma unroll
  for (int i = 0; i < 4; i++) {
    int nl = ty + i * 8;
    float x = tile[tx][nl];  // = W[k0+tx][n0+nl]
    ushort h = f2bf(x);
    ushort lw = f2bf(x - bf2f(h));
    hi[(size_t)(n0 + nl) * DMODEL + k0 + tx] = h;
    lo[(size_t)(n0 + nl) * DMODEL + k0 + tx] = lw;
  }
}

// ---------------------------------------------------------------------------
// Split-bf16 GEMM: Y[M=4096][N=768] = X f32 @ W + bias, via hi/lo 3-MFMA.
// Tile 64x64, BK=32, 4 waves (2x2 of 32x32), 16x16x32 MFMA.
// MODE 0: write hi/lo bf16 to [B,H,S,DK] with scale (Q: 1/8, K: 1)
// MODE 1: write bf16 to VT [B,H,DK,S]
// MODE 2: write f32 to out [M,768]
// ---------------------------------------------------------------------------
template <int MODE>
__global__ __launch_bounds__(256) void gemm_kernel(
    const float* __restrict__ X, const ushort* __restrict__ WTh,
    const ushort* __restrict__ WTl, const float* __restrict__ bias, float scale,
    ushort* __restrict__ outH, ushort* __restrict__ outL,
    float* __restrict__ outF) {
  __shared__ ushort Ah[64 * 40], Al[64 * 40], Bh[64 * 40], Bl[64 * 40];
  const int t = threadIdx.x;
  const int l = t & 63, w = t >> 6;
  const int wr = w >> 1, wc = w & 1;
  const int lr = l & 15, lg = l >> 4, koff = lg * 8;
  const int m0 = blockIdx.y * 64, n0 = blockIdx.x * 64;
  const int srow = t >> 2, soff = (t & 3) * 8;

  f32x4 acc[2][2] = {};

  for (int kk = 0; kk < DMODEL; kk += 32) {
    __syncthreads();
    {
      const float* src = X + (size_t)(m0 + srow) * DMODEL + kk + soff;
      float4 f0 = *(const float4*)src;
      float4 f1 = *(const float4*)(src + 4);
      float xv[8] = {f0.x, f0.y, f0.z, f0.w, f1.x, f1.y, f1.z, f1.w};
      uint32_t hw[4], lw[4];
#pragma unroll
      for (int j = 0; j < 4; j++) {
        ushort h0 = f2bf(xv[2 * j]);
        ushort h1 = f2bf(xv[2 * j + 1]);
        ushort l0 = f2bf(xv[2 * j] - bf2f(h0));
        ushort l1 = f2bf(xv[2 * j + 1] - bf2f(h1));
        hw[j] = (uint32_t)h0 | ((uint32_t)h1 << 16);
        lw[j] = (uint32_t)l0 | ((uint32_t)l1 << 16);
      }
      *(uint4*)&Ah[srow * 40 + soff] = make_uint4(hw[0], hw[1], hw[2], hw[3]);
      *(uint4*)&Al[srow * 40 + soff] = make_uint4(lw[0], lw[1], lw[2], lw[3]);
      const size_t boff = (size_t)(n0 + srow) * DMODEL + kk + soff;
      *(uint4*)&Bh[srow * 40 + soff] = *(const uint4*)&WTh[boff];
      *(uint4*)&Bl[srow * 40 + soff] = *(const uint4*)&WTl[boff];
    }
    __syncthreads();
    shortx8 ah[2], al[2], bh[2], bl[2];
#pragma unroll
    for (int ti = 0; ti < 2; ti++) {
      int r = (wr * 32 + ti * 16 + lr) * 40 + koff;
      ah[ti] = *(const shortx8*)&Ah[r];
      al[ti] = *(const shortx8*)&Al[r];
    }
#pragma unroll
    for (int tj = 0; tj < 2; tj++) {
      int r = (wc * 32 + tj * 16 + lr) * 40 + koff;
      bh[tj] = *(const shortx8*)&Bh[r];
      bl[tj] = *(const shortx8*)&Bl[r];
    }
#pragma unroll
    for (int ti = 0; ti < 2; ti++)
#pragma unroll
      for (int tj = 0; tj < 2; tj++) {
        acc[ti][tj] = MFMA(ah[ti], bh[tj], acc[ti][tj]);
        acc[ti][tj] = MFMA(ah[ti], bl[tj], acc[ti][tj]);
        acc[ti][tj] = MFMA(al[ti], bh[tj], acc[ti][tj]);
      }
  }

  // Epilogue. C layout: col = lane&15, row = (lane>>4)*4 + reg  [m89-verified]
#pragma unroll
  for (int ti = 0; ti < 2; ti++)
#pragma unroll
    for (int tj = 0; tj < 2; tj++) {
      int n = n0 + wc * 32 + tj * 16 + lr;
      float bv_ = bias[n];
#pragma unroll
      for (int r = 0; r < 4; r++) {
        int m = m0 + wr * 32 + ti * 16 + lg * 4 + r;
        float y = acc[ti][tj][r] + bv_;
        if (MODE == 0) {
          y *= scale;
          ushort hh = f2bf(y);
          ushort ll = f2bf(y - bf2f(hh));
          int b = m >> 11, s = m & 2047, hd = n >> 6, d = n & 63;
          size_t idx = (((size_t)(b * NHEADS + hd) * SEQ) + s) * DK + d;
          outH[idx] = hh;
          outL[idx] = ll;
        } else if (MODE == 1) {
          int b = m >> 11, s = m & 2047, hd = n >> 6, d = n & 63;
          size_t idx = (((size_t)(b * NHEADS + hd) * DK) + d) * SEQ + s;
          outH[idx] = f2bf(y);
        } else {
          outF[(size_t)m * DMODEL + n] = y;
        }
      }
    }
}

// ---------------------------------------------------------------------------
// Flash attention: grid (S/64, H, B), 256 threads = 4 waves x 16 q-rows.
// Q (pre-scaled by 1/8) split hi/lo in regs; K split hi/lo staged in LDS;
// V^T staged in LDS. Online softmax f32; P -> bf16 via wave-private LDS.
// ---------------------------------------------------------------------------
__global__ __launch_bounds__(256) void attn_kernel(
    const ushort* __restrict__ Qh, const ushort* __restrict__ Ql,
    const ushort* __restrict__ Kh, const ushort* __restrict__ Kl,
    const ushort* __restrict__ Vt, float* __restrict__ O) {
  __shared__ ushort Ksh[64][72], Ksl[64][72], Vsh[64][72];
  __shared__ ushort Psh[4][16][72];
  const int t = threadIdx.x;
  const int l = t & 63, w = t >> 6;
  const int lr = l & 15, lg = l >> 4, koff = lg * 8;
  const int qt = blockIdx.x, h = blockIdx.y, b = blockIdx.z;
  const int s0 = qt * 64;
  const size_t bh_off = ((size_t)(b * NHEADS + h)) * SEQ * DK;
  const size_t vt_off = ((size_t)(b * NHEADS + h)) * DK * SEQ;

  shortx8 qfh[2], qfl[2];
  {
    size_t qrow = bh_off + (size_t)(s0 + w * 16 + lr) * DK;
    qfh[0] = *(const shortx8*)&Qh[qrow + koff];
    qfh[1] = *(const shortx8*)&Qh[qrow + 32 + koff];
    qfl[0] = *(const shortx8*)&Ql[qrow + koff];
    qfl[1] = *(const shortx8*)&Ql[qrow + 32 + koff];
  }
  f32x4 oacc[4] = {};
  float mrun[4], lrun[4];
#pragma unroll
  for (int r = 0; r < 4; r++) { mrun[r] = -1e30f; lrun[r] = 0.f; }

  for (int sk0 = 0; sk0 < SEQ; sk0 += 64) {
    __syncthreads();
    for (int c = t; c < 512; c += 256) {
      int row = c >> 3, off = (c & 7) * 8;
      *(uint4*)&Ksh[row][off] =
          *(const uint4*)&Kh[bh_off + (size_t)(sk0 + row) * DK + off];
      *(uint4*)&Ksl[row][off] =
          *(const uint4*)&Kl[bh_off + (size_t)(sk0 + row) * DK + off];
      *(uint4*)&Vsh[row][off] =
          *(const uint4*)&Vt[vt_off + (size_t)row * SEQ + sk0 + off];
    }
    __syncthreads();

    // scores: 4 key-tiles of 16, 6 MFMAs each (hh x2, hl x2, lh x2)
    f32x4 sc[4];
#pragma unroll
    for (int kt = 0; kt < 4; kt++) {
      int krow = kt * 16 + lr;
      shortx8 kh0 = *(const shortx8*)&Ksh[krow][koff];
      shortx8 kh1 = *(const shortx8*)&Ksh[krow][32 + koff];
      shortx8 kl0 = *(const shortx8*)&Ksl[krow][koff];
      shortx8 kl1 = *(const shortx8*)&Ksl[krow][32 + koff];
      f32x4 s_ = {};
      s_ = MFMA(qfh[0], kh0, s_);
      s_ = MFMA(qfh[1], kh1, s_);
      s_ = MFMA(qfh[0], kl0, s_);
      s_ = MFMA(qfh[1], kl1, s_);
      s_ = MFMA(qfl[0], kh0, s_);
      s_ = MFMA(qfl[1], kh1, s_);
      sc[kt] = s_;
    }

    // online softmax per q-row (rows lg*4+r; key col = kt*16 + lr)
#pragma unroll
    for (int r = 0; r < 4; r++) {
      float vmax = fmaxf(fmaxf(sc[0][r], sc[1][r]), fmaxf(sc[2][r], sc[3][r]));
#pragma unroll
      for (int msk = 1; msk < 16; msk <<= 1)
        vmax = fmaxf(vmax, __shfl_xor(vmax, msk));
      float mnew = fmaxf(mrun[r], vmax);
      float fac = __expf(mrun[r] - mnew);
      mrun[r] = mnew;
      float psum = 0.f;
#pragma unroll
      for (int kt = 0; kt < 4; kt++) {
        float p = __expf(sc[kt][r] - mnew);
        sc[kt][r] = p;
        psum += p;
      }
#pragma unroll
      for (int msk = 1; msk < 16; msk <<= 1) psum += __shfl_xor(psum, msk);
      lrun[r] = lrun[r] * fac + psum;
#pragma unroll
      for (int dt = 0; dt < 4; dt++) oacc[dt][r] *= fac;
#pragma unroll
      for (int kt = 0; kt < 4; kt++)
        Psh[w][lg * 4 + r][kt * 16 + lr] = f2bf(sc[kt][r]);
    }
    __syncthreads();  // safety ordering for Psh write->read

    // PV: O[16q][64d] += P[16q][64k] * V^T
    shortx8 pa0 = *(const shortx8*)&Psh[w][lr][koff];
    shortx8 pa1 = *(const shortx8*)&Psh[w][lr][32 + koff];
#pragma unroll
    for (int dt = 0; dt < 4; dt++) {
      shortx8 vb0 = *(const shortx8*)&Vsh[dt * 16 + lr][koff];
      shortx8 vb1 = *(const shortx8*)&Vsh[dt * 16 + lr][32 + koff];
      oacc[dt] = MFMA(pa0, vb0, oacc[dt]);
      oacc[dt] = MFMA(pa1, vb1, oacc[dt]);
    }
  }

#pragma unroll
  for (int r = 0; r < 4; r++) {
    float inv = 1.0f / lrun[r];
    size_t orow =
        ((size_t)b * SEQ + s0 + w * 16 + lg * 4 + r) * DMODEL + h * DK;
#pragma unroll
    for (int dt = 0; dt < 4; dt++)
      O[orow + dt * 16 + lr] = oacc[dt][r] * inv;
  }
}

// ---------------------------------------------------------------------------
extern "C" void kernel_launch(void* const* d_in, const int* in_sizes, int n_in,
                              void* d_out, int out_size, void* d_ws,
                              size_t ws_size, hipStream_t stream) {
  const float* q = (const float*)d_in[0];
  const float* k = (const float*)d_in[1];
  const float* v = (const float*)d_in[2];
  const float* Wq = (const float*)d_in[3];
  const float* bq = (const float*)d_in[4];
  const float* Wk = (const float*)d_in[5];
  const float* bk = (const float*)d_in[6];
  const float* Wv = (const float*)d_in[7];
  const float* bv = (const float*)d_in[8];
  const float* Wo = (const float*)d_in[9];
  const float* bo = (const float*)d_in[10];
  float* out = (float*)d_out;

  constexpr size_t WMAT = (size_t)DMODEL * DMODEL;          // 589824
  constexpr size_t WT_ELEMS = 4 * WMAT;                     // all 4 matrices
  constexpr size_t QKV_ELEMS = (size_t)BATCH * NHEADS * SEQ * DK;  // 3145728

  ushort* WThi = (ushort*)d_ws;
  ushort* WTlo = WThi + WT_ELEMS;
  ushort* QhHi = WTlo + WT_ELEMS;
  ushort* QhLo = QhHi + QKV_ELEMS;
  ushort* KhHi = QhLo + QKV_ELEMS;
  ushort* KhLo = KhHi + QKV_ELEMS;
  ushort* VtB = KhLo + QKV_ELEMS;
  float* Obuf = (float*)(VtB + QKV_ELEMS);

  wsplit_kernel<<<dim3(24, 24, 4), 256, 0, stream>>>(Wq, Wk, Wv, Wo, WThi,
                                                     WTlo);
  dim3 gg(DMODEL / 64, (BATCH * SEQ) / 64);
  gemm_kernel<0><<<gg, 256, 0, stream>>>(q, WThi, WTlo, bq, 0.125f, QhHi, QhLo,
                                         nullptr);
  gemm_kernel<0><<<gg, 256, 0, stream>>>(k, WThi + WMAT, WTlo + WMAT, bk, 1.0f,
                                         KhHi, KhLo, nullptr);
  gemm_kernel<1><<<gg, 256, 0, stream>>>(v, WThi + 2 * WMAT, WTlo + 2 * WMAT,
                                         bv, 1.0f, VtB, nullptr, nullptr);
  attn_kernel<<<dim3(SEQ / 64, NHEADS, BATCH), 256, 0, stream>>>(
      QhHi, QhLo, KhHi, KhLo, VtB, Obuf);
  gemm_kernel<2><<<gg, 256, 0, stream>>>(Obuf, WThi + 3 * WMAT,
                                         WTlo + 3 * WMAT, bo, 1.0f, nullptr,
                                         nullptr, out);
}